// Round 2
// baseline (532.674 us; speedup 1.0000x reference)
//
#include <hip/hip_runtime.h>
#include <cstddef>

#define TEMP_MIN_F 1e-4f

constexpr int kS = 1024;   // frames
constexpr int kB = 256;    // batch
constexpr int kN = 256;    // channels
constexpr int kM = 512;    // z rows
constexpr int kE = 64;     // experts
constexpr int kT = kS - 1; // valid attention steps

constexpr int kThreads = 1024;
constexpr int kWaves   = kThreads / 64; // 16
constexpr int kR       = 8;             // rows batched per wave per sweep
constexpr int kSweepRows = kWaves * kR; // 128
constexpr int kSweeps  = kS / kSweepRows; // 8

__device__ __forceinline__ float waveReduceSum(float v) {
#pragma unroll
  for (int off = 32; off >= 1; off >>= 1) v += __shfl_xor(v, off, 64);
  return v;
}
__device__ __forceinline__ float waveReduceMin(float v) {
#pragma unroll
  for (int off = 32; off >= 1; off >>= 1) v = fminf(v, __shfl_xor(v, off, 64));
  return v;
}
__device__ __forceinline__ float waveReduceMax(float v) {
#pragma unroll
  for (int off = 32; off >= 1; off >>= 1) v = fmaxf(v, __shfl_xor(v, off, 64));
  return v;
}

// One block per batch element b. 1024 threads = 16 waves (50% CU occupancy;
// grid=256 pins one block per CU, so block size is the only occupancy lever).
// Pass A: d[t] = sum_i |ctx[t,b,i] - z[i,b]|, 8 rows batched per wave for MLP.
// Softmax over t in LDS. Pass B: c0/c1 weighted sums, same 8-row batching
// (re-read hits L2/L3 - FETCH_SIZE shows HBM sees context exactly once).
// Tail: conv-collapse GEMV, MLP, softmax over experts.
__global__ __launch_bounds__(1024)
void gating_fused(const float* __restrict__ context,
                  const float* __restrict__ z,
                  const float* __restrict__ conv_w,
                  const float* __restrict__ conv_b,
                  const float* __restrict__ W1,
                  const float* __restrict__ W2,
                  const float* __restrict__ t1p,
                  const float* __restrict__ t2p,
                  float* __restrict__ out) {
  const int b    = blockIdx.x;
  const int tid  = threadIdx.x;
  const int wave = tid >> 6;
  const int lane = tid & 63;

  __shared__ __align__(16) float s_w[kS];                 // distances -> weights
  __shared__ __align__(16) float s_z[kM];                 // z[:, b]
  __shared__ __align__(16) float s_c[2][kN];              // reduced c0, c1
  __shared__ __align__(16) float s_part[kWaves][2 * kN];  // per-wave partials (32 KB)
  __shared__ __align__(16) float s_emb[kN];
  __shared__ float s_h[kE];
  __shared__ float s_red[kWaves + 2];

  // stage z column b
  for (int m = tid; m < kM; m += kThreads) s_z[m] = z[(size_t)m * kB + b];
  __syncthreads();

  const float temp1  = fmaxf(fabsf(t1p[0]), TEMP_MIN_F);
  const float inv_t1 = 1.0f / temp1;

  const float4 zz = ((const float4*)s_z)[lane]; // z_cur[b, 4l..4l+3]

  // ---- Pass A: L1 distances, 8 independent loads in flight per wave ----
  for (int sweep = 0; sweep < kSweeps; ++sweep) {
    const int t0 = sweep * kSweepRows + wave * kR;
    const float* base = context + ((size_t)t0 * kB + b) * kN + 4 * lane;
    float4 x[kR];
#pragma unroll
    for (int r = 0; r < kR; ++r)
      x[r] = *(const float4*)(base + (size_t)r * kB * kN); // row t0+r (<=1023, always in-bounds)
    float d[kR];
#pragma unroll
    for (int r = 0; r < kR; ++r)
      d[r] = fabsf(x[r].x - zz.x) + fabsf(x[r].y - zz.y) +
             fabsf(x[r].z - zz.z) + fabsf(x[r].w - zz.w);
    // 8 interleaved butterfly chains (ILP across rows)
#pragma unroll
    for (int off = 32; off >= 1; off >>= 1) {
#pragma unroll
      for (int r = 0; r < kR; ++r) d[r] += __shfl_xor(d[r], off, 64);
    }
    if (lane == 0) {
#pragma unroll
      for (int r = 0; r < kR; ++r)
        if (t0 + r < kT) s_w[t0 + r] = d[r];
    }
  }
  __syncthreads();

  // ---- softmax over t: w_t = exp((dmin - d_t)/temp1) / l ----
  float mloc = 1e30f;
  for (int t = tid; t < kT; t += kThreads) mloc = fminf(mloc, s_w[t]);
  mloc = waveReduceMin(mloc);
  if (lane == 0) s_red[wave] = mloc;
  __syncthreads();
  if (tid == 0) {
    float mm = s_red[0];
#pragma unroll
    for (int w = 1; w < kWaves; ++w) mm = fminf(mm, s_red[w]);
    s_red[kWaves] = mm;
  }
  __syncthreads();
  const float dmin = s_red[kWaves];

  float lsum = 0.f;
  for (int t = tid; t < kT; t += kThreads) {
    float e = expf((dmin - s_w[t]) * inv_t1);
    s_w[t] = e;
    lsum += e;
  }
  lsum = waveReduceSum(lsum);
  if (lane == 0) s_red[wave] = lsum;
  __syncthreads();
  if (tid == 0) {
    float tot = 0.f;
#pragma unroll
    for (int w = 0; w < kWaves; ++w) tot += s_red[w];
    s_red[kWaves + 1] = 1.0f / tot;
  }
  __syncthreads();
  const float inv_l = s_red[kWaves + 1];

  // ---- Pass B: weighted sums c0, c1 with 8-row batching ----
  float4 a0 = make_float4(0.f, 0.f, 0.f, 0.f);
  float4 a1 = make_float4(0.f, 0.f, 0.f, 0.f);
  for (int sweep = 0; sweep < kSweeps; ++sweep) {
    const int t0 = sweep * kSweepRows + wave * kR;
    const float* base = context + ((size_t)t0 * kB + b) * kN + 4 * lane;
    float4 x[kR];
#pragma unroll
    for (int r = 0; r < kR; ++r)
      x[r] = *(const float4*)(base + (size_t)r * kB * kN);
#pragma unroll
    for (int r = 0; r < kR; ++r) {
      const int t = t0 + r;
      const float w0 = (t < kT) ? s_w[t] : 0.f;     // weight for c0 (row t)
      const float w1 = (t > 0) ? s_w[t - 1] : 0.f;  // weight for c1 (row t as frame t-1's successor)
      a0.x += w0 * x[r].x; a0.y += w0 * x[r].y; a0.z += w0 * x[r].z; a0.w += w0 * x[r].w;
      a1.x += w1 * x[r].x; a1.y += w1 * x[r].y; a1.z += w1 * x[r].z; a1.w += w1 * x[r].w;
    }
  }
  ((float4*)&s_part[wave][0])[lane] =
      make_float4(a0.x * inv_l, a0.y * inv_l, a0.z * inv_l, a0.w * inv_l);
  ((float4*)&s_part[wave][kN])[lane] =
      make_float4(a1.x * inv_l, a1.y * inv_l, a1.z * inv_l, a1.w * inv_l);
  __syncthreads();
  if (tid < kN) {
    float p0 = 0.f, p1 = 0.f;
#pragma unroll
    for (int w = 0; w < kWaves; ++w) {
      p0 += s_part[w][tid];
      p1 += s_part[w][kN + tid];
    }
    s_c[0][tid] = p0;
    s_c[1][tid] = p1;
  }
  __syncthreads();

  // ---- embedding[o] = conv_w[o,:,0].c0 + conv_w[o,:,1].c1 + conv_b[o] ----
  const float4 cc0 = ((const float4*)&s_c[0][0])[lane];
  const float4 cc1 = ((const float4*)&s_c[1][0])[lane];
  for (int o = wave; o < kN; o += kWaves) {
    const float4* wrow = (const float4*)(conv_w + (size_t)o * (2 * kN));
    float4 wa = wrow[2 * lane];       // (i=4l,k=0),(4l,1),(4l+1,0),(4l+1,1)
    float4 wb = wrow[2 * lane + 1];   // (4l+2,0),(4l+2,1),(4l+3,0),(4l+3,1)
    float acc = wa.x * cc0.x + wa.y * cc1.x + wa.z * cc0.y + wa.w * cc1.y +
                wb.x * cc0.z + wb.y * cc1.z + wb.z * cc0.w + wb.w * cc1.w;
    acc = waveReduceSum(acc);
    if (lane == 0) s_emb[o] = acc + conv_b[o];
  }
  __syncthreads();

  // ---- h[e] = relu(combined . W1[e,:]) ; combined = [embedding(256); z(512)] ----
  for (int e = wave; e < kE; e += kWaves) {
    const float* wr = W1 + (size_t)e * (kN + kM);
    float acc = 0.f;
#pragma unroll
    for (int jj = 0; jj < 12; ++jj) {
      int j = lane + 64 * jj;
      float cj = (j < kN) ? s_emb[j] : s_z[j - kN];
      acc += wr[j] * cj;
    }
    acc = waveReduceSum(acc);
    if (lane == 0) s_h[e] = fmaxf(acc, 0.f);
  }
  __syncthreads();

  // ---- mlp + softmax over E (wave 0, lane = e2) ----
  if (wave == 0) {
    const float temp2 = fmaxf(fabsf(t2p[0]), TEMP_MIN_F);
    float acc = 0.f;
    const float* w2r = W2 + (size_t)lane * kE;
#pragma unroll
    for (int e = 0; e < kE; ++e) acc += w2r[e] * s_h[e];
    float logit = -acc / temp2;
    float mx = waveReduceMax(logit);
    float ex = expf(logit - mx);
    float ssum = waveReduceSum(ex);
    out[(size_t)lane * kB + b] = ex / ssum;
  }
}

extern "C" void kernel_launch(void* const* d_in, const int* in_sizes, int n_in,
                              void* d_out, int out_size, void* d_ws, size_t ws_size,
                              hipStream_t stream) {
  const float* context = (const float*)d_in[0];
  const float* z       = (const float*)d_in[1];
  // d_in[2] = D — structurally [I_N | 0]; D@z == z[:N,:], so unused.
  const float* conv_w  = (const float*)d_in[3];
  const float* conv_b  = (const float*)d_in[4];
  const float* W1      = (const float*)d_in[5];
  const float* W2      = (const float*)d_in[6];
  const float* t1      = (const float*)d_in[7];
  const float* t2      = (const float*)d_in[8];
  float* out = (float*)d_out;

  hipLaunchKernelGGL(gating_fused, dim3(kB), dim3(kThreads), 0, stream,
                     context, z, conv_w, conv_b, W1, W2, t1, t2, out);
}

// Round 4
// 451.233 us; speedup vs baseline: 1.1805x; 1.1805x over previous
//
#include <hip/hip_runtime.h>
#include <cstddef>

#define TEMP_MIN_F 1e-4f

constexpr int kS = 1024;   // frames
constexpr int kB = 256;    // batch
constexpr int kN = 256;    // channels
constexpr int kM = 512;    // z rows
constexpr int kE = 64;     // experts
constexpr int kT = kS - 1; // valid attention steps

constexpr int kChunks   = 8;            // t-chunks for the two heavy passes
constexpr int kChunkRows = kS / kChunks; // 128 rows per chunk

// workspace layout (floats)
constexpr size_t kWOff = 0;                        // weights/distances: [b*1024 + t], t < 1023
constexpr size_t kWLen = (size_t)kB * kS;          // 262144 floats (1 MB)
constexpr size_t kPOff = kWOff + kWLen;            // partials: [(b*8+c)*512 + {j | 256+j}]
constexpr size_t kPLen = (size_t)kB * kChunks * 2 * kN; // 1048576 floats (4 MB)

__device__ __forceinline__ float waveReduceSum(float v) {
#pragma unroll
  for (int off = 32; off >= 1; off >>= 1) v += __shfl_xor(v, off, 64);
  return v;
}
__device__ __forceinline__ float waveReduceMin(float v) {
#pragma unroll
  for (int off = 32; off >= 1; off >>= 1) v = fminf(v, __shfl_xor(v, off, 64));
  return v;
}
__device__ __forceinline__ float waveReduceMax(float v) {
#pragma unroll
  for (int off = 32; off >= 1; off >>= 1) v = fmaxf(v, __shfl_xor(v, off, 64));
  return v;
}

// ---- k1: distances d[t,b] = sum_i |ctx[t,b,i] - z[i,b]| ----
// grid (8, 256): block (c,b) handles 128 t-rows for batch b. 256 thr = 4 waves,
// wave handles 32 rows in 8 batches of kR=4 (4 float4 loads in flight; ~50 VGPR
// fits the 64-VGPR cap for 8 waves/EU -> full occupancy, no spill).
__global__ __launch_bounds__(256)
void k_dist(const float* __restrict__ context,
            const float* __restrict__ z,
            float* __restrict__ ws_d) {
  const int c = blockIdx.x, b = blockIdx.y;
  const int tid = threadIdx.x, wave = tid >> 6, lane = tid & 63;

  __shared__ __align__(16) float s_z[kN]; // only z[:N, b] matters (D = [I|0])
  if (tid < kN) s_z[tid] = z[(size_t)tid * kB + b];
  __syncthreads();
  const float4 zz = ((const float4*)s_z)[lane];

#pragma unroll
  for (int it = 0; it < 8; ++it) {
    const int t0 = c * kChunkRows + wave * 32 + it * 4;
    const float* base = context + ((size_t)t0 * kB + b) * kN + 4 * lane;
    float4 x[4];
#pragma unroll
    for (int r = 0; r < 4; ++r)
      x[r] = *(const float4*)(base + (size_t)r * kB * kN);
    float d[4];
#pragma unroll
    for (int r = 0; r < 4; ++r)
      d[r] = fabsf(x[r].x - zz.x) + fabsf(x[r].y - zz.y) +
             fabsf(x[r].z - zz.z) + fabsf(x[r].w - zz.w);
#pragma unroll
    for (int off = 32; off >= 1; off >>= 1) {
#pragma unroll
      for (int r = 0; r < 4; ++r) d[r] += __shfl_xor(d[r], off, 64);
    }
    if (lane == 0) {
#pragma unroll
      for (int r = 0; r < 4; ++r)
        if (t0 + r < kT) ws_d[(size_t)b * kS + t0 + r] = d[r];
    }
  }
}

// ---- k2: per-b softmax over t, in place: w[t] = exp((dmin-d)/t1) / l ----
__global__ __launch_bounds__(256)
void k_soft(float* __restrict__ ws_d, const float* __restrict__ t1p) {
  const int b = blockIdx.x;
  const int tid = threadIdx.x, wave = tid >> 6, lane = tid & 63;
  float* col = ws_d + (size_t)b * kS;

  __shared__ float s_red[6];
  const float inv_t1 = 1.0f / fmaxf(fabsf(t1p[0]), TEMP_MIN_F);

  float mloc = 1e30f;
  for (int t = tid; t < kT; t += 256) mloc = fminf(mloc, col[t]);
  mloc = waveReduceMin(mloc);
  if (lane == 0) s_red[wave] = mloc;
  __syncthreads();
  if (tid == 0)
    s_red[4] = fminf(fminf(s_red[0], s_red[1]), fminf(s_red[2], s_red[3]));
  __syncthreads();
  const float dmin = s_red[4];

  float lsum = 0.f;
  for (int t = tid; t < kT; t += 256) {
    float e = expf((dmin - col[t]) * inv_t1);
    col[t] = e; // each t owned by exactly one thread
    lsum += e;
  }
  lsum = waveReduceSum(lsum);
  if (lane == 0) s_red[wave] = lsum;
  __syncthreads();
  if (tid == 0)
    s_red[5] = 1.0f / (s_red[0] + s_red[1] + s_red[2] + s_red[3]);
  __syncthreads();
  const float inv_l = s_red[5];
  for (int t = tid; t < kT; t += 256) col[t] *= inv_l;
}

// ---- k3: partial weighted sums per (b, chunk) ----
// c0_part[j] = sum_{t in chunk} w[t]*ctx[t,b,j]; c1_part[j] = sum w[t-1]*ctx[t,b,j]
__global__ __launch_bounds__(256)
void k_wsum(const float* __restrict__ context,
            const float* __restrict__ ws_w,
            float* __restrict__ part) {
  const int c = blockIdx.x, b = blockIdx.y;
  const int tid = threadIdx.x, wave = tid >> 6, lane = tid & 63;
  const float* wcol = ws_w + (size_t)b * kS;

  float4 a0 = make_float4(0.f, 0.f, 0.f, 0.f);
  float4 a1 = make_float4(0.f, 0.f, 0.f, 0.f);
#pragma unroll
  for (int it = 0; it < 8; ++it) {
    const int t0 = c * kChunkRows + wave * 32 + it * 4;
    const float* base = context + ((size_t)t0 * kB + b) * kN + 4 * lane;
    float4 x[4];
#pragma unroll
    for (int r = 0; r < 4; ++r)
      x[r] = *(const float4*)(base + (size_t)r * kB * kN);
#pragma unroll
    for (int r = 0; r < 4; ++r) {
      const int t = t0 + r;
      const float w0 = (t < kT) ? wcol[t] : 0.f;     // weight for c0 (row t)
      const float w1 = (t > 0) ? wcol[t - 1] : 0.f;  // weight for c1 (row t = frame (t-1)+1)
      a0.x += w0 * x[r].x; a0.y += w0 * x[r].y; a0.z += w0 * x[r].z; a0.w += w0 * x[r].w;
      a1.x += w1 * x[r].x; a1.y += w1 * x[r].y; a1.z += w1 * x[r].z; a1.w += w1 * x[r].w;
    }
  }

  __shared__ __align__(16) float s_part[4][2 * kN]; // 8 KB
  ((float4*)&s_part[wave][0])[lane] = a0;
  ((float4*)&s_part[wave][kN])[lane] = a1;
  __syncthreads();
  if (tid < kN) {
    float p0 = 0.f, p1 = 0.f;
#pragma unroll
    for (int w = 0; w < 4; ++w) {
      p0 += s_part[w][tid];
      p1 += s_part[w][kN + tid];
    }
    const size_t o = ((size_t)b * kChunks + c) * (2 * kN);
    part[o + tid] = p0;
    part[o + kN + tid] = p1;
  }
}

// ---- k4: reduce partials + conv-collapse GEMV + MLP + expert softmax ----
// embedding[o] = conv_w[o,:,0].c0 + conv_w[o,:,1].c1 + conv_b[o]
// h = relu([emb; z].W1^T); mlp = h.W2^T; out[:,b] = softmax(-mlp/t2)
__global__ __launch_bounds__(512)
void k_tail(const float* __restrict__ part,
            const float* __restrict__ z,
            const float* __restrict__ conv_w,
            const float* __restrict__ conv_b,
            const float* __restrict__ W1,
            const float* __restrict__ W2,
            const float* __restrict__ t2p,
            float* __restrict__ out) {
  const int b = blockIdx.x;
  const int tid = threadIdx.x, wave = tid >> 6, lane = tid & 63;

  __shared__ __align__(16) float s_z[kM];
  __shared__ __align__(16) float s_c[2][kN];
  __shared__ __align__(16) float s_emb[kN];
  __shared__ float s_h[kE];

  for (int m = tid; m < kM; m += 512) s_z[m] = z[(size_t)m * kB + b];
  if (tid < kN) {
    float p0 = 0.f, p1 = 0.f;
#pragma unroll
    for (int c = 0; c < kChunks; ++c) {
      const size_t o = ((size_t)b * kChunks + c) * (2 * kN);
      p0 += part[o + tid];
      p1 += part[o + kN + tid];
    }
    s_c[0][tid] = p0;
    s_c[1][tid] = p1;
  }
  __syncthreads();

  const float4 cc0 = ((const float4*)&s_c[0][0])[lane];
  const float4 cc1 = ((const float4*)&s_c[1][0])[lane];
  for (int o = wave; o < kN; o += 8) {
    const float4* wrow = (const float4*)(conv_w + (size_t)o * (2 * kN));
    float4 wa = wrow[2 * lane];       // (i=4l,k=0),(4l,1),(4l+1,0),(4l+1,1)
    float4 wb = wrow[2 * lane + 1];   // (4l+2,0),(4l+2,1),(4l+3,0),(4l+3,1)
    float acc = wa.x * cc0.x + wa.y * cc1.x + wa.z * cc0.y + wa.w * cc1.y +
                wb.x * cc0.z + wb.y * cc1.z + wb.z * cc0.w + wb.w * cc1.w;
    acc = waveReduceSum(acc);
    if (lane == 0) s_emb[o] = acc + conv_b[o];
  }
  __syncthreads();

  for (int e = wave; e < kE; e += 8) {
    const float* wr = W1 + (size_t)e * (kN + kM);
    float acc = 0.f;
#pragma unroll
    for (int jj = 0; jj < 12; ++jj) {
      int j = lane + 64 * jj;
      float cj = (j < kN) ? s_emb[j] : s_z[j - kN];
      acc += wr[j] * cj;
    }
    acc = waveReduceSum(acc);
    if (lane == 0) s_h[e] = fmaxf(acc, 0.f);
  }
  __syncthreads();

  if (wave == 0) {
    const float temp2 = fmaxf(fabsf(t2p[0]), TEMP_MIN_F);
    float acc = 0.f;
    const float* w2r = W2 + (size_t)lane * kE;
#pragma unroll
    for (int e = 0; e < kE; ++e) acc += w2r[e] * s_h[e];
    float logit = -acc / temp2;
    float mx = waveReduceMax(logit);
    float ex = expf(logit - mx);
    float ssum = waveReduceSum(ex);
    out[(size_t)lane * kB + b] = ex / ssum;
  }
}

extern "C" void kernel_launch(void* const* d_in, const int* in_sizes, int n_in,
                              void* d_out, int out_size, void* d_ws, size_t ws_size,
                              hipStream_t stream) {
  const float* context = (const float*)d_in[0];
  const float* z       = (const float*)d_in[1];
  // d_in[2] = D — structurally [I_N | 0]; D@z == z[:N,:], so unused.
  const float* conv_w  = (const float*)d_in[3];
  const float* conv_b  = (const float*)d_in[4];
  const float* W1      = (const float*)d_in[5];
  const float* W2      = (const float*)d_in[6];
  const float* t1      = (const float*)d_in[7];
  const float* t2      = (const float*)d_in[8];
  float* out = (float*)d_out;

  float* ws   = (float*)d_ws;
  float* ws_d = ws + kWOff; // 1 MB: distances -> normalized weights (in place)
  float* part = ws + kPOff; // 4 MB: per-(b,chunk) c0/c1 partials

  hipLaunchKernelGGL(k_dist, dim3(kChunks, kB), dim3(256), 0, stream,
                     context, z, ws_d);
  hipLaunchKernelGGL(k_soft, dim3(kB), dim3(256), 0, stream, ws_d, t1);
  hipLaunchKernelGGL(k_wsum, dim3(kChunks, kB), dim3(256), 0, stream,
                     context, ws_d, part);
  hipLaunchKernelGGL(k_tail, dim3(kB), dim3(512), 0, stream,
                     part, z, conv_w, conv_b, W1, W2, t2, out);
}

// Round 5
// 408.313 us; speedup vs baseline: 1.3046x; 1.1051x over previous
//
#include <hip/hip_runtime.h>
#include <cstddef>

#define TEMP_MIN_F 1e-4f

constexpr int kS = 1024;   // frames
constexpr int kB = 256;    // batch
constexpr int kN = 256;    // channels
constexpr int kM = 512;    // z rows
constexpr int kE = 64;     // experts
constexpr int kT = kS - 1; // valid attention steps

constexpr int kChunks     = 8;              // t-chunks (grid.x)
constexpr int kChunkRows  = kS / kChunks;   // 128 rows per block
constexpr int kRowsPerWave = 32;            // own rows per wave (4 waves/block)

// workspace layout (floats)
constexpr size_t kMOff = 0;                                  // m per (b,chunk): 2048
constexpr size_t kLOff = kMOff + (size_t)kB * kChunks;       // l per (b,chunk): 2048
constexpr size_t kCOff = kLOff + (size_t)kB * kChunks;       // c0/c1: [ (b*8+c)*512 + {j | 256+j} ]

__device__ __forceinline__ float waveReduceSum(float v) {
#pragma unroll
  for (int off = 32; off >= 1; off >>= 1) v += __shfl_xor(v, off, 64);
  return v;
}
__device__ __forceinline__ float waveReduceMax(float v) {
#pragma unroll
  for (int off = 32; off >= 1; off >>= 1) v = fmaxf(v, __shfl_xor(v, off, 64));
  return v;
}

// ---- k_fused: single pass over context with online softmax ----
// weight[t] = exp((dmin - d[t]) / T) / l  (softmax of -d/T over t).
// Wave streams rows t0..t0+32 (33rd row = boundary, c1-only). Maintains
// running min m, l, w_prev and alpha-rescaled accumulators:
//   c0 = sum_t w[t] x[t],  c1 = sum_t w[t] x[t+1]   (w relative to current m)
// Per-(b,chunk) partial (m, l, c0, c1) written to ws; tail does flash-merge.
__global__ __launch_bounds__(256)
void k_fused(const float* __restrict__ context,
             const float* __restrict__ z,
             const float* __restrict__ t1p,
             float* __restrict__ ws_m,
             float* __restrict__ ws_l,
             float* __restrict__ ws_c) {
  const int c = blockIdx.x, b = blockIdx.y;
  const int tid = threadIdx.x, wave = tid >> 6, lane = tid & 63;
  const float inv_t1 = 1.0f / fmaxf(fabsf(t1p[0]), TEMP_MIN_F);

  __shared__ __align__(16) float s_z[kN]; // z[:N, b] (D = [I|0] => z_obs = z[:N])
  if (tid < kN) s_z[tid] = z[(size_t)tid * kB + b];
  __syncthreads();
  const float4 zz = ((const float4*)s_z)[lane];

  const int t0 = c * kChunkRows + wave * kRowsPerWave;
  const size_t rowStride = (size_t)kB * kN;
  const float* base = context + ((size_t)t0 * kB + b) * kN + 4 * lane;

  // rows streamed: own 32 + 1 boundary row (skip if it would be row 1024)
  const int nRows = (t0 + kRowsPerWave < kS) ? kRowsPerWave + 1 : kRowsPerWave;

  float m = 1e30f, l = 0.f, w_prev = 0.f;
  float4 c0 = make_float4(0.f, 0.f, 0.f, 0.f);
  float4 c1 = make_float4(0.f, 0.f, 0.f, 0.f);

  float4 xc = *(const float4*)base; // prefetch row t0
  for (int r = 0; r < nRows; ++r) {
    const int t = t0 + r;
    float4 xn;
    if (r + 1 < nRows) xn = *(const float4*)(base + (size_t)(r + 1) * rowStride);

    const bool own = (r < kRowsPerWave) && (t < kT);
    if (own) {
      float d = fabsf(xc.x - zz.x) + fabsf(xc.y - zz.y) +
                fabsf(xc.z - zz.z) + fabsf(xc.w - zz.w);
      d = waveReduceSum(d); // full L1 distance, wave-uniform
      const float m_new = fminf(m, d);
      const float alpha = expf((m_new - m) * inv_t1); // <=1; first iter: exp(-huge)=0
      const float w_t   = expf((m_new - d) * inv_t1);
      const float wp    = w_prev * alpha;             // w[t-1] rescaled to m_new
      l = l * alpha + w_t;
      c0.x = c0.x * alpha + w_t * xc.x; c0.y = c0.y * alpha + w_t * xc.y;
      c0.z = c0.z * alpha + w_t * xc.z; c0.w = c0.w * alpha + w_t * xc.w;
      c1.x = c1.x * alpha + wp * xc.x;  c1.y = c1.y * alpha + wp * xc.y;
      c1.z = c1.z * alpha + wp * xc.z;  c1.w = c1.w * alpha + wp * xc.w;
      w_prev = w_t;
      m = m_new;
    } else {
      // boundary row (r==32) or t==1023: contributes only w[t-1]*x[t] to c1
      c1.x += w_prev * xc.x; c1.y += w_prev * xc.y;
      c1.z += w_prev * xc.z; c1.w += w_prev * xc.w;
    }
    xc = xn;
  }

  // ---- merge the block's 4 waves (flash-style) ----
  __shared__ float s_m[4], s_l[4];
  __shared__ __align__(16) float s_cc[4][2 * kN]; // 8 KB
  if (lane == 0) s_m[wave] = m;
  __syncthreads();
  const float m_blk = fminf(fminf(s_m[0], s_m[1]), fminf(s_m[2], s_m[3]));
  const float aw = expf((m_blk - m) * inv_t1);
  if (lane == 0) s_l[wave] = l * aw;
  ((float4*)&s_cc[wave][0])[lane] =
      make_float4(c0.x * aw, c0.y * aw, c0.z * aw, c0.w * aw);
  ((float4*)&s_cc[wave][kN])[lane] =
      make_float4(c1.x * aw, c1.y * aw, c1.z * aw, c1.w * aw);
  __syncthreads();

  const size_t pc = (size_t)b * kChunks + c;
  if (tid < kN) {
    float p0 = s_cc[0][tid] + s_cc[1][tid] + s_cc[2][tid] + s_cc[3][tid];
    float p1 = s_cc[0][kN + tid] + s_cc[1][kN + tid] +
               s_cc[2][kN + tid] + s_cc[3][kN + tid];
    ws_c[pc * (2 * kN) + tid] = p0;
    ws_c[pc * (2 * kN) + kN + tid] = p1;
  }
  if (tid == 0) {
    ws_m[pc] = m_blk;
    ws_l[pc] = s_l[0] + s_l[1] + s_l[2] + s_l[3];
  }
}

// ---- k_tail: flash-merge 8 chunks + conv-collapse GEMV + MLP + softmax ----
__global__ __launch_bounds__(512)
void k_tail(const float* __restrict__ ws_m,
            const float* __restrict__ ws_l,
            const float* __restrict__ ws_c,
            const float* __restrict__ z,
            const float* __restrict__ conv_w,
            const float* __restrict__ conv_b,
            const float* __restrict__ W1,
            const float* __restrict__ W2,
            const float* __restrict__ t1p,
            const float* __restrict__ t2p,
            float* __restrict__ out) {
  const int b = blockIdx.x;
  const int tid = threadIdx.x, wave = tid >> 6, lane = tid & 63;
  const float inv_t1 = 1.0f / fmaxf(fabsf(t1p[0]), TEMP_MIN_F);

  __shared__ __align__(16) float s_z[kM];
  __shared__ __align__(16) float s_c[2][kN];
  __shared__ __align__(16) float s_emb[kN];
  __shared__ float s_h[kE];
  __shared__ float s_mt[kChunks], s_lt[kChunks], s_alpha[kChunks];
  __shared__ float s_invl;

  for (int mm = tid; mm < kM; mm += 512) s_z[mm] = z[(size_t)mm * kB + b];
  if (tid < kChunks) {
    s_mt[tid] = ws_m[(size_t)b * kChunks + tid];
    s_lt[tid] = ws_l[(size_t)b * kChunks + tid];
  }
  __syncthreads();
  if (tid < kChunks) {
    float mg = s_mt[0];
#pragma unroll
    for (int cc = 1; cc < kChunks; ++cc) mg = fminf(mg, s_mt[cc]);
    s_alpha[tid] = expf((mg - s_mt[tid]) * inv_t1);
  }
  __syncthreads();
  if (tid == 0) {
    float lt = 0.f;
#pragma unroll
    for (int cc = 0; cc < kChunks; ++cc) lt += s_alpha[cc] * s_lt[cc];
    s_invl = 1.0f / lt;
  }
  __syncthreads();
  if (tid < kN) {
    float p0 = 0.f, p1 = 0.f;
#pragma unroll
    for (int cc = 0; cc < kChunks; ++cc) {
      const size_t o = ((size_t)b * kChunks + cc) * (2 * kN);
      p0 += s_alpha[cc] * ws_c[o + tid];
      p1 += s_alpha[cc] * ws_c[o + kN + tid];
    }
    s_c[0][tid] = p0 * s_invl;
    s_c[1][tid] = p1 * s_invl;
  }
  __syncthreads();

  // embedding[o] = conv_w[o,:,0].c0 + conv_w[o,:,1].c1 + conv_b[o]
  const float4 cc0 = ((const float4*)&s_c[0][0])[lane];
  const float4 cc1 = ((const float4*)&s_c[1][0])[lane];
  for (int o = wave; o < kN; o += 8) {
    const float4* wrow = (const float4*)(conv_w + (size_t)o * (2 * kN));
    float4 wa = wrow[2 * lane];       // (i=4l,k=0),(4l,1),(4l+1,0),(4l+1,1)
    float4 wb = wrow[2 * lane + 1];   // (4l+2,0),(4l+2,1),(4l+3,0),(4l+3,1)
    float acc = wa.x * cc0.x + wa.y * cc1.x + wa.z * cc0.y + wa.w * cc1.y +
                wb.x * cc0.z + wb.y * cc1.z + wb.z * cc0.w + wb.w * cc1.w;
    acc = waveReduceSum(acc);
    if (lane == 0) s_emb[o] = acc + conv_b[o];
  }
  __syncthreads();

  // h[e] = relu([emb; z] . W1[e,:])
  for (int e = wave; e < kE; e += 8) {
    const float* wr = W1 + (size_t)e * (kN + kM);
    float acc = 0.f;
#pragma unroll
    for (int jj = 0; jj < 12; ++jj) {
      int j = lane + 64 * jj;
      float cj = (j < kN) ? s_emb[j] : s_z[j - kN];
      acc += wr[j] * cj;
    }
    acc = waveReduceSum(acc);
    if (lane == 0) s_h[e] = fmaxf(acc, 0.f);
  }
  __syncthreads();

  // mlp + softmax over experts (wave 0, lane = expert)
  if (wave == 0) {
    const float temp2 = fmaxf(fabsf(t2p[0]), TEMP_MIN_F);
    float acc = 0.f;
    const float* w2r = W2 + (size_t)lane * kE;
#pragma unroll
    for (int e = 0; e < kE; ++e) acc += w2r[e] * s_h[e];
    float logit = -acc / temp2;
    float mx = waveReduceMax(logit);
    float ex = expf(logit - mx);
    float ssum = waveReduceSum(ex);
    out[(size_t)lane * kB + b] = ex / ssum;
  }
}

extern "C" void kernel_launch(void* const* d_in, const int* in_sizes, int n_in,
                              void* d_out, int out_size, void* d_ws, size_t ws_size,
                              hipStream_t stream) {
  const float* context = (const float*)d_in[0];
  const float* z       = (const float*)d_in[1];
  // d_in[2] = D — structurally [I_N | 0]; D@z == z[:N,:], so unused.
  const float* conv_w  = (const float*)d_in[3];
  const float* conv_b  = (const float*)d_in[4];
  const float* W1      = (const float*)d_in[5];
  const float* W2      = (const float*)d_in[6];
  const float* t1      = (const float*)d_in[7];
  const float* t2      = (const float*)d_in[8];
  float* out = (float*)d_out;

  float* ws   = (float*)d_ws;
  float* ws_m = ws + kMOff;
  float* ws_l = ws + kLOff;
  float* ws_c = ws + kCOff;

  hipLaunchKernelGGL(k_fused, dim3(kChunks, kB), dim3(256), 0, stream,
                     context, z, t1, ws_m, ws_l, ws_c);
  hipLaunchKernelGGL(k_tail, dim3(kB), dim3(512), 0, stream,
                     ws_m, ws_l, ws_c, z, conv_w, conv_b, W1, W2, t1, t2, out);
}